// Round 5
// baseline (242.349 us; speedup 1.0000x reference)
//
#include <hip/hip_runtime.h>
#include <math.h>

#define SEQ 4096
#define DIM 1024

typedef unsigned short u16;
typedef __attribute__((ext_vector_type(8))) short short8;     // 8 x bf16 (4 VGPRs)
typedef __attribute__((ext_vector_type(4))) float floatx4;    // MFMA accumulator
typedef __attribute__((ext_vector_type(4))) unsigned short us4;

__device__ __forceinline__ float bf2f(u16 u) {
    union { unsigned int i; float f; } c; c.i = ((unsigned int)u) << 16; return c.f;
}
__device__ __forceinline__ u16 f2bf(float f) {
    union { float f; unsigned int i; } c; c.f = f;
    return (u16)((c.i + 0x7fffu + ((c.i >> 16) & 1u)) >> 16);  // RNE
}
__device__ __forceinline__ void gload_lds16(const u16* g, u16* l) {
    __builtin_amdgcn_global_load_lds((const __attribute__((address_space(1))) void*)g,
                                     (__attribute__((address_space(3))) void*)l, 16, 0, 0);
}

// ---------------------------------------------------------------------------
// NT MFMA GEMM, 64x128 tile (BM=64 rows, BN=128 cols), BK=32, 4 waves (2x2):
// wave = (wm, wn), each wave computes 32x64 via 2x4 mfma_16x16x32_bf16.
// Rationale (R5): R4 was latency-bound with grid-limited occupancy (2 blocks/
// CU); 64x128 gives 24KB LDS/block -> 6 blocks/CU resident and 2-4x more
// blocks per grid. LDS double-buffered single-barrier pipeline; prefetch
// issued right after the barrier. XOR-swizzled chunk layout (R4: conflicts=0).
// MODE 0: bf16 out; col0<2048 -> C (scale0 if col0<1024 else 1.0);
//         col0>=2048 -> transposed write into VtOut (V^T, us4-packed).
// MODE 1: bf16 out, skip blocks above causal diagonal (scores).
// MODE 2: fp32 out, split-K over blockIdx.z (1024-chunks, causal k-bound);
//         chunk 0 -> Cv direct, chunks 1..3 -> compact partial buffers.
// ---------------------------------------------------------------------------
template <int MODE>
__global__ __launch_bounds__(256) void gemm_nt(const u16* __restrict__ A,
                                               const u16* __restrict__ B,
                                               void* __restrict__ Cv,
                                               float* __restrict__ Ppart,
                                               u16* __restrict__ VtOut,
                                               int lda, int ldb, int ldc, int Kdim,
                                               float scale0) {
    const int row0 = blockIdx.y * 64;
    const int col0 = blockIdx.x * 128;
    if (MODE == 1 && col0 > row0) return;
    int kbeg = 0, kend = Kdim, chunk = 0;
    if (MODE == 2) {
        chunk = blockIdx.z;
        kbeg = chunk << 10;
        const int klim = row0 + 64;
        if (kbeg >= klim) return;
        kend = min(kbeg + 1024, klim);
    }

    __shared__ u16 As[2][2048];  // 2 x 4KB (64 rows x 32 k)
    __shared__ u16 Bs[2][4096];  // 2 x 8KB (128 rows x 32 k)

    const int tid  = threadIdx.x;
    const int wave = tid >> 6;
    const int lane = tid & 63;
    const int wm = wave & 1;   // m half (32 rows)
    const int wn = wave >> 1;  // n half (64 cols)

    // A staging: 256 16B-slots; wave w fills [w*64, w*64+64).
    // slot s holds global chunk (r = s>>2, q = (s&3) ^ ((s>>3)&3))
    const int ra = (wave << 4) + (lane >> 2);
    const int qa = ((lane & 3) ^ ((lane >> 3) & 3)) * 8;
    const u16* aP = A + (size_t)(row0 + ra) * lda + kbeg + qa;
    // B staging: 512 slots; wave w fills [w*128, w*128+128) via two glds.
    const int s0 = wave * 128 + lane;
    const int s1 = s0 + 64;
    const int rb0 = s0 >> 2, qb0 = ((s0 & 3) ^ ((s0 >> 3) & 3)) * 8;
    const int rb1 = s1 >> 2, qb1 = ((s1 & 3) ^ ((s1 >> 3) & 3)) * 8;
    const u16* bP0 = B + (size_t)(col0 + rb0) * ldb + kbeg + qb0;
    const u16* bP1 = B + (size_t)(col0 + rb1) * ldb + kbeg + qb1;
    const int la = wave * 512;
    const int lb = wave * 1024;

    floatx4 acc[2][4] = {};
    const int niter = (kend - kbeg) >> 5;
    const int frow = lane & 15;
    // swizzled k-chunk offset for fragment reads (elements)
    const int xq = (((lane >> 4) ^ ((frow >> 1) & 3))) * 8;

    gload_lds16(aP, &As[0][la]);
    gload_lds16(bP0, &Bs[0][lb]);
    gload_lds16(bP1, &Bs[0][lb + 512]);
    aP += 32; bP0 += 32; bP1 += 32;

    for (int it = 0; it < niter; ++it) {
        const int cur = it & 1;
        __syncthreads();  // drains tile-it loads (in flight a full iteration)
        if (it + 1 < niter) {
            const int nxt = cur ^ 1;
            gload_lds16(aP, &As[nxt][la]);
            gload_lds16(bP0, &Bs[nxt][lb]);
            gload_lds16(bP1, &Bs[nxt][lb + 512]);
            aP += 32; bP0 += 32; bP1 += 32;
        }
        __builtin_amdgcn_sched_barrier(0);  // keep prefetch issue ahead of compute
        short8 af[2], bfr[4];
#pragma unroll
        for (int t = 0; t < 2; ++t)
            af[t] = *(const short8*)&As[cur][(wm * 32 + t * 16 + frow) * 32 + xq];
#pragma unroll
        for (int t = 0; t < 4; ++t)
            bfr[t] = *(const short8*)&Bs[cur][(wn * 64 + t * 16 + frow) * 32 + xq];
#pragma unroll
        for (int mt = 0; mt < 2; ++mt)
#pragma unroll
            for (int nt = 0; nt < 4; ++nt)
                acc[mt][nt] = __builtin_amdgcn_mfma_f32_16x16x32_bf16(
                    af[mt], bfr[nt], acc[mt][nt], 0, 0, 0);
    }

    // epilogue: C/D layout col=lane&15, row=(lane>>4)*4+reg
    const int cr = (lane >> 4) * 4;
    const int cc = lane & 15;
    if (MODE == 2) {
        float* dst;
        if (chunk == 0) {
            dst = (float*)Cv;
        } else {
            const ptrdiff_t poff[3] = {0, (ptrdiff_t)3072 * 1024, (ptrdiff_t)5120 * 1024};
            dst = Ppart + poff[chunk - 1] - (ptrdiff_t)(chunk << 10) * 1024;
        }
#pragma unroll
        for (int mt = 0; mt < 2; ++mt)
#pragma unroll
            for (int nt = 0; nt < 4; ++nt)
#pragma unroll
                for (int r = 0; r < 4; ++r) {
                    const int row = row0 + wm * 32 + mt * 16 + cr + r;
                    const int col = col0 + wn * 64 + nt * 16 + cc;
                    dst[(size_t)row * ldc + col] = acc[mt][nt][r];
                }
    } else if (MODE == 0 && col0 >= 2048) {
        // V columns: write V^T directly. 4 consecutive regs = 4 consecutive
        // rows -> contiguous in Vt[col][row], pack as us4 (8B).
#pragma unroll
        for (int mt = 0; mt < 2; ++mt)
#pragma unroll
            for (int nt = 0; nt < 4; ++nt) {
                const int row = row0 + wm * 32 + mt * 16 + cr;
                const int col = (col0 - 2048) + wn * 64 + nt * 16 + cc;
                us4 o = { f2bf(acc[mt][nt][0]), f2bf(acc[mt][nt][1]),
                          f2bf(acc[mt][nt][2]), f2bf(acc[mt][nt][3]) };
                *(us4*)&VtOut[(size_t)col * SEQ + row] = o;
            }
    } else {
        u16* dst = (u16*)Cv;
        const float sc = (MODE == 0 && col0 < 1024) ? scale0 : 1.0f;
#pragma unroll
        for (int mt = 0; mt < 2; ++mt)
#pragma unroll
            for (int nt = 0; nt < 4; ++nt)
#pragma unroll
                for (int r = 0; r < 4; ++r) {
                    const int row = row0 + wm * 32 + mt * 16 + cr + r;
                    const int col = col0 + wn * 64 + nt * 16 + cc;
                    dst[(size_t)row * ldc + col] = f2bf(acc[mt][nt][r] * sc);
                }
    }
}

// fp32 [k][n] -> bf16 [n][k]; blockIdx.z selects Wq/Wk/Wv, stacked [3072][1024]
__global__ __launch_bounds__(256) void transpose_cast(const float* __restrict__ W0,
                                                      const float* __restrict__ W1,
                                                      const float* __restrict__ W2,
                                                      u16* __restrict__ Wt) {
    __shared__ float tile[32][33];
    const float* W = (blockIdx.z == 0) ? W0 : (blockIdx.z == 1) ? W1 : W2;
    u16* out = Wt + (size_t)blockIdx.z * DIM * DIM;
    const int bx = blockIdx.x * 32;  // n block
    const int by = blockIdx.y * 32;  // k block
    const int tx = threadIdx.x & 31;
    const int ty = (threadIdx.x >> 5) * 4;
#pragma unroll
    for (int r = 0; r < 4; ++r)
        tile[ty + r][tx] = W[(size_t)(by + ty + r) * DIM + bx + tx];
    __syncthreads();
#pragma unroll
    for (int r = 0; r < 4; ++r)
        out[(size_t)(bx + ty + r) * DIM + by + tx] = f2bf(tile[tx][ty + r]);
}

// fp32 -> bf16 flat cast (x)
__global__ __launch_bounds__(256) void cast_bf16(const float* __restrict__ X,
                                                 u16* __restrict__ Xb) {
    const size_t i = ((size_t)blockIdx.x * 256 + threadIdx.x) * 4;
    const float4 v = *(const float4*)(X + i);
    us4 o = { f2bf(v.x), f2bf(v.y), f2bf(v.z), f2bf(v.w) };
    *(us4*)(Xb + i) = o;
}

// causal softmax, single-pass (register-cached), in-place bf16.
// Zeroes only cols [n, diag-block edge) — all PV ever reads.
__global__ __launch_bounds__(256) void softmax_causal_bf16(u16* __restrict__ S) {
    __shared__ float red[4];
    __shared__ float bc;
    const int i = blockIdx.x;
    u16* row = S + (size_t)i * SEQ;
    const int n = i + 1;
    const int tid = threadIdx.x;
    const int zend = (i & ~127) + 128;

    float v[16];
    float m = -3.4e38f;
#pragma unroll
    for (int t = 0; t < 16; ++t) {
        const int j = tid + (t << 8);
        if (j < n) { v[t] = bf2f(row[j]); m = fmaxf(m, v[t]); }
    }
#pragma unroll
    for (int o = 32; o > 0; o >>= 1) m = fmaxf(m, __shfl_down(m, o));
    if ((tid & 63) == 0) red[tid >> 6] = m;
    __syncthreads();
    if (tid == 0) bc = fmaxf(fmaxf(red[0], red[1]), fmaxf(red[2], red[3]));
    __syncthreads();
    m = bc;

    float s = 0.f;
#pragma unroll
    for (int t = 0; t < 16; ++t) {
        const int j = tid + (t << 8);
        if (j < n) { v[t] = __expf(v[t] - m); s += v[t]; }
    }
#pragma unroll
    for (int o = 32; o > 0; o >>= 1) s += __shfl_down(s, o);
    if ((tid & 63) == 0) red[tid >> 6] = s;
    __syncthreads();
    if (tid == 0) bc = 1.0f / (red[0] + red[1] + red[2] + red[3]);
    __syncthreads();
    const float inv = bc;

#pragma unroll
    for (int t = 0; t < 16; ++t) {
        const int j = tid + (t << 8);
        if (j < n) row[j] = f2bf(v[t] * inv);
        else if (j < zend) row[j] = 0;
    }
}

// O[row] += partials, rows 1024..4095; one block per row, float4 lanes
__global__ __launch_bounds__(256) void reduce_pv(float* __restrict__ O,
                                                 const float* __restrict__ P) {
    const int r = blockIdx.x;  // 0..3071
    const int row = 1024 + r;
    const int col = threadIdx.x * 4;
    float4 a = *(const float4*)(O + (size_t)row * 1024 + col);
    const float4 b1 = *(const float4*)(P + (size_t)r * 1024 + col);
    a.x += b1.x; a.y += b1.y; a.z += b1.z; a.w += b1.w;
    if (row >= 2048) {
        const float4 b2 = *(const float4*)(P + (size_t)3072 * 1024 +
                                           (size_t)(row - 2048) * 1024 + col);
        a.x += b2.x; a.y += b2.y; a.z += b2.z; a.w += b2.w;
    }
    if (row >= 3072) {
        const float4 b3 = *(const float4*)(P + (size_t)5120 * 1024 +
                                           (size_t)(row - 3072) * 1024 + col);
        a.x += b3.x; a.y += b3.y; a.z += b3.z; a.w += b3.w;
    }
    *(float4*)(O + (size_t)row * 1024 + col) = a;
}

extern "C" void kernel_launch(void* const* d_in, const int* in_sizes, int n_in,
                              void* d_out, int out_size, void* d_ws, size_t ws_size,
                              hipStream_t stream) {
    const float* x  = (const float*)d_in[0];
    const float* Wq = (const float*)d_in[1];
    const float* Wk = (const float*)d_in[2];
    const float* Wv = (const float*)d_in[3];

    // ws: xb 8MB | Wt 6MB | QK [4096][2048] 16MB | Vt 8MB | S 32MB | Ppart 24MB = 94 MB
    u16* xb    = (u16*)d_ws;
    u16* Wt    = xb  + (size_t)SEQ * DIM;
    u16* QK    = Wt  + (size_t)3072 * DIM;
    u16* Vt    = QK  + (size_t)SEQ * 2048;
    u16* S     = Vt  + (size_t)DIM * SEQ;
    float* Ppart = (float*)(S + (size_t)SEQ * SEQ);

    cast_bf16<<<SEQ * DIM / 1024, 256, 0, stream>>>(x, xb);
    transpose_cast<<<dim3(32, 32, 3), 256, 0, stream>>>(Wq, Wk, Wv, Wt);

    // [Q|K] = x @ [Wq|Wk] (Q scaled 1/32); V columns stream out as V^T. 1536 blocks.
    gemm_nt<0><<<dim3(24, 64), 256, 0, stream>>>(
        xb, Wt, QK, nullptr, Vt, DIM, DIM, 2048, DIM, 0.03125f);

    // S = Q @ K^T, lower-triangle blocks. 1056 active blocks.
    gemm_nt<1><<<dim3(32, 64), 256, 0, stream>>>(
        QK, QK + 1024, S, nullptr, nullptr, 2048, 2048, SEQ, DIM, 1.0f);

    softmax_causal_bf16<<<SEQ, 256, 0, stream>>>(S);

    // O = P @ Vt^T, split-K (1024-chunks, causal-bounded). 1280 active blocks.
    gemm_nt<2><<<dim3(8, 64, 4), 256, 0, stream>>>(
        S, Vt, d_out, Ppart, nullptr, SEQ, SEQ, DIM, SEQ, 1.0f);

    reduce_pv<<<3072, 256, 0, stream>>>((float*)d_out, Ppart);
}

// Round 6
// 211.074 us; speedup vs baseline: 1.1482x; 1.1482x over previous
//
#include <hip/hip_runtime.h>
#include <math.h>

#define SEQ 4096
#define DIM 1024

typedef unsigned short u16;
typedef __attribute__((ext_vector_type(8))) short short8;     // 8 x bf16 (4 VGPRs)
typedef __attribute__((ext_vector_type(4))) float floatx4;    // MFMA accumulator
typedef __attribute__((ext_vector_type(4))) unsigned short us4;

__device__ __forceinline__ float bf2f(u16 u) {
    union { unsigned int i; float f; } c; c.i = ((unsigned int)u) << 16; return c.f;
}
__device__ __forceinline__ u16 f2bf(float f) {
    union { float f; unsigned int i; } c; c.f = f;
    return (u16)((c.i + 0x7fffu + ((c.i >> 16) & 1u)) >> 16);  // RNE
}
__device__ __forceinline__ void gload_lds16(const u16* g, u16* l) {
    __builtin_amdgcn_global_load_lds((const __attribute__((address_space(1))) void*)g,
                                     (__attribute__((address_space(3))) void*)l, 16, 0, 0);
}

// ---------------------------------------------------------------------------
// NT MFMA GEMM, 128x128 tile, BK=32, 4 waves (2x2), 4x4 mfma_16x16x32_bf16.
// R6: manual software pipeline. Triple-buffered LDS (3x16KB=48KB); raw
// s_barrier (asm, no compiler vmcnt(0) drain); manual s_waitcnt vmcnt(4):
// each wave issues exactly 4 global_load_lds per tile, so vmcnt(4) waits for
// its own current-tile loads while next tile's 4 stay in flight (AITER
// pattern: never drain to 0 in steady state). Tile it+2 DMA targets buffer
// (it-1)%3 — safe: every wave finished reading tile it-1 before reaching
// barrier it (MFMA issue requires the lgkm wait on those ds_reads).
// XOR-swizzled chunk layout (R4: conflicts=0).
// MODE 0: bf16 out; col0<2048 -> C (scale0 if col0<1024 else 1.0);
//         col0>=2048 -> transposed write into VtOut (V^T, us4-packed).
// MODE 1: bf16 out, skip blocks above causal diagonal (scores).
// MODE 2: fp32 out, split-K over blockIdx.z (1024-chunks, causal k-bound);
//         chunk 0 -> Cv direct, chunks 1..3 -> compact partial buffers.
// ---------------------------------------------------------------------------
template <int MODE>
__global__ __launch_bounds__(256) void gemm_nt(const u16* __restrict__ A,
                                               const u16* __restrict__ B,
                                               void* __restrict__ Cv,
                                               float* __restrict__ Ppart,
                                               u16* __restrict__ VtOut,
                                               int lda, int ldb, int ldc, int Kdim,
                                               float scale0) {
    const int row0 = blockIdx.y * 128;
    const int col0 = blockIdx.x * 128;
    if (MODE == 1 && col0 > row0) return;
    int kbeg = 0, kend = Kdim, chunk = 0;
    if (MODE == 2) {
        chunk = blockIdx.z;
        kbeg = chunk << 10;
        const int klim = row0 + 128;
        if (kbeg >= klim) return;
        kend = min(kbeg + 1024, klim);
    }

    __shared__ u16 As[3][4096];  // 3 x 8KB
    __shared__ u16 Bs[3][4096];

    const int tid  = threadIdx.x;
    const int wave = tid >> 6;
    const int lane = tid & 63;
    const int wm = wave & 1;
    const int wn = wave >> 1;

    // staging: 512 16B-slots per tile; wave w fills slots [w*128, w*128+128).
    // slot s <- global chunk (r = s>>2, q = (s&3) ^ ((s>>3)&3))
    const int s0 = wave * 128 + lane;
    const int s1 = s0 + 64;
    const int r0s = s0 >> 2, q0s = ((s0 & 3) ^ ((s0 >> 3) & 3)) * 8;
    const int r1s = s1 >> 2, q1s = ((s1 & 3) ^ ((s1 >> 3) & 3)) * 8;
    const u16* aP0 = A + (size_t)(row0 + r0s) * lda + kbeg + q0s;
    const u16* aP1 = A + (size_t)(row0 + r1s) * lda + kbeg + q1s;
    const u16* bP0 = B + (size_t)(col0 + r0s) * ldb + kbeg + q0s;
    const u16* bP1 = B + (size_t)(col0 + r1s) * ldb + kbeg + q1s;
    const int l0 = wave * 1024;

    floatx4 acc[4][4] = {};
    const int niter = (kend - kbeg) >> 5;   // >= 4 in all launches
    const int frow = lane & 15;
    // swizzled k-chunk offset for fragment reads (elements)
    const int xq = (((lane >> 4) ^ ((frow >> 1) & 3))) * 8;

    // prologue: tiles 0,1 -> buffers 0,1 (8 loads outstanding per wave)
    gload_lds16(aP0, &As[0][l0]);
    gload_lds16(aP1, &As[0][l0 + 512]);
    gload_lds16(bP0, &Bs[0][l0]);
    gload_lds16(bP1, &Bs[0][l0 + 512]);
    aP0 += 32; aP1 += 32; bP0 += 32; bP1 += 32;
    gload_lds16(aP0, &As[1][l0]);
    gload_lds16(aP1, &As[1][l0 + 512]);
    gload_lds16(bP0, &Bs[1][l0]);
    gload_lds16(bP1, &Bs[1][l0 + 512]);
    aP0 += 32; aP1 += 32; bP0 += 32; bP1 += 32;

    auto compute_tile = [&](int c) {
        short8 af[4], bfr[4];
#pragma unroll
        for (int t = 0; t < 4; ++t) {
            af[t]  = *(const short8*)&As[c][(wm * 64 + t * 16 + frow) * 32 + xq];
            bfr[t] = *(const short8*)&Bs[c][(wn * 64 + t * 16 + frow) * 32 + xq];
        }
#pragma unroll
        for (int mt = 0; mt < 4; ++mt)
#pragma unroll
            for (int nt = 0; nt < 4; ++nt)
                acc[mt][nt] = __builtin_amdgcn_mfma_f32_16x16x32_bf16(
                    af[mt], bfr[nt], acc[mt][nt], 0, 0, 0);
    };

    int cur = 0, pre = 2;
    for (int it = 0; it < niter - 2; ++it) {
        // own current-tile loads done; next tile's 4 stay in flight
        asm volatile("s_waitcnt vmcnt(4)\n\ts_barrier" ::: "memory");
        {
            short8 af[4], bfr[4];
#pragma unroll
            for (int t = 0; t < 4; ++t) {
                af[t]  = *(const short8*)&As[cur][(wm * 64 + t * 16 + frow) * 32 + xq];
                bfr[t] = *(const short8*)&Bs[cur][(wn * 64 + t * 16 + frow) * 32 + xq];
            }
            // prefetch tile it+2 into buffer (it+2)%3 (== (it-1)%3, already
            // fully consumed by all waves before this barrier)
            gload_lds16(aP0, &As[pre][l0]);
            gload_lds16(aP1, &As[pre][l0 + 512]);
            gload_lds16(bP0, &Bs[pre][l0]);
            gload_lds16(bP1, &Bs[pre][l0 + 512]);
            aP0 += 32; aP1 += 32; bP0 += 32; bP1 += 32;
#pragma unroll
            for (int mt = 0; mt < 4; ++mt)
#pragma unroll
                for (int nt = 0; nt < 4; ++nt)
                    acc[mt][nt] = __builtin_amdgcn_mfma_f32_16x16x32_bf16(
                        af[mt], bfr[nt], acc[mt][nt], 0, 0, 0);
        }
        cur = (cur == 2) ? 0 : cur + 1;
        pre = (pre == 2) ? 0 : pre + 1;
    }
    // tile niter-2: 8 outstanding -> wait own 4, leave last tile's 4 in flight
    asm volatile("s_waitcnt vmcnt(4)\n\ts_barrier" ::: "memory");
    compute_tile(cur);
    cur = (cur == 2) ? 0 : cur + 1;
    // tile niter-1: final drain
    asm volatile("s_waitcnt vmcnt(0)\n\ts_barrier" ::: "memory");
    compute_tile(cur);

    // epilogue: C/D layout col=lane&15, row=(lane>>4)*4+reg
    const int cr = (lane >> 4) * 4;
    const int cc = lane & 15;
    if (MODE == 2) {
        float* dst;
        if (chunk == 0) {
            dst = (float*)Cv;
        } else {
            const ptrdiff_t poff[3] = {0, (ptrdiff_t)3072 * 1024, (ptrdiff_t)5120 * 1024};
            dst = Ppart + poff[chunk - 1] - (ptrdiff_t)(chunk << 10) * 1024;
        }
#pragma unroll
        for (int mt = 0; mt < 4; ++mt)
#pragma unroll
            for (int nt = 0; nt < 4; ++nt)
#pragma unroll
                for (int r = 0; r < 4; ++r) {
                    const int row = row0 + wm * 64 + mt * 16 + cr + r;
                    const int col = col0 + wn * 64 + nt * 16 + cc;
                    dst[(size_t)row * ldc + col] = acc[mt][nt][r];
                }
    } else if (MODE == 0 && col0 >= 2048) {
        // V columns: write V^T directly. 4 consecutive regs = 4 consecutive
        // rows -> contiguous in Vt[col][row], pack as us4 (8B).
#pragma unroll
        for (int mt = 0; mt < 4; ++mt)
#pragma unroll
            for (int nt = 0; nt < 4; ++nt) {
                const int row = row0 + wm * 64 + mt * 16 + cr;
                const int col = (col0 - 2048) + wn * 64 + nt * 16 + cc;
                us4 o = { f2bf(acc[mt][nt][0]), f2bf(acc[mt][nt][1]),
                          f2bf(acc[mt][nt][2]), f2bf(acc[mt][nt][3]) };
                *(us4*)&VtOut[(size_t)col * SEQ + row] = o;
            }
    } else {
        u16* dst = (u16*)Cv;
        const float sc = (MODE == 0 && col0 < 1024) ? scale0 : 1.0f;
#pragma unroll
        for (int mt = 0; mt < 4; ++mt)
#pragma unroll
            for (int nt = 0; nt < 4; ++nt)
#pragma unroll
                for (int r = 0; r < 4; ++r) {
                    const int row = row0 + wm * 64 + mt * 16 + cr + r;
                    const int col = col0 + wn * 64 + nt * 16 + cc;
                    dst[(size_t)row * ldc + col] = f2bf(acc[mt][nt][r] * sc);
                }
    }
}

// fp32 [k][n] -> bf16 [n][k]; blockIdx.z selects Wq/Wk/Wv, stacked [3072][1024]
__global__ __launch_bounds__(256) void transpose_cast(const float* __restrict__ W0,
                                                      const float* __restrict__ W1,
                                                      const float* __restrict__ W2,
                                                      u16* __restrict__ Wt) {
    __shared__ float tile[32][33];
    const float* W = (blockIdx.z == 0) ? W0 : (blockIdx.z == 1) ? W1 : W2;
    u16* out = Wt + (size_t)blockIdx.z * DIM * DIM;
    const int bx = blockIdx.x * 32;  // n block
    const int by = blockIdx.y * 32;  // k block
    const int tx = threadIdx.x & 31;
    const int ty = (threadIdx.x >> 5) * 4;
#pragma unroll
    for (int r = 0; r < 4; ++r)
        tile[ty + r][tx] = W[(size_t)(by + ty + r) * DIM + bx + tx];
    __syncthreads();
#pragma unroll
    for (int r = 0; r < 4; ++r)
        out[(size_t)(bx + ty + r) * DIM + by + tx] = f2bf(tile[tx][ty + r]);
}

// fp32 -> bf16 flat cast (x)
__global__ __launch_bounds__(256) void cast_bf16(const float* __restrict__ X,
                                                 u16* __restrict__ Xb) {
    const size_t i = ((size_t)blockIdx.x * 256 + threadIdx.x) * 4;
    const float4 v = *(const float4*)(X + i);
    us4 o = { f2bf(v.x), f2bf(v.y), f2bf(v.z), f2bf(v.w) };
    *(us4*)(Xb + i) = o;
}

// causal softmax, single-pass (register-cached), in-place bf16.
// Zeroes only cols [n, diag-block edge) — all PV ever reads.
__global__ __launch_bounds__(256) void softmax_causal_bf16(u16* __restrict__ S) {
    __shared__ float red[4];
    __shared__ float bc;
    const int i = blockIdx.x;
    u16* row = S + (size_t)i * SEQ;
    const int n = i + 1;
    const int tid = threadIdx.x;
    const int zend = (i & ~127) + 128;

    float v[16];
    float m = -3.4e38f;
#pragma unroll
    for (int t = 0; t < 16; ++t) {
        const int j = tid + (t << 8);
        if (j < n) { v[t] = bf2f(row[j]); m = fmaxf(m, v[t]); }
    }
#pragma unroll
    for (int o = 32; o > 0; o >>= 1) m = fmaxf(m, __shfl_down(m, o));
    if ((tid & 63) == 0) red[tid >> 6] = m;
    __syncthreads();
    if (tid == 0) bc = fmaxf(fmaxf(red[0], red[1]), fmaxf(red[2], red[3]));
    __syncthreads();
    m = bc;

    float s = 0.f;
#pragma unroll
    for (int t = 0; t < 16; ++t) {
        const int j = tid + (t << 8);
        if (j < n) { v[t] = __expf(v[t] - m); s += v[t]; }
    }
#pragma unroll
    for (int o = 32; o > 0; o >>= 1) s += __shfl_down(s, o);
    if ((tid & 63) == 0) red[tid >> 6] = s;
    __syncthreads();
    if (tid == 0) bc = 1.0f / (red[0] + red[1] + red[2] + red[3]);
    __syncthreads();
    const float inv = bc;

#pragma unroll
    for (int t = 0; t < 16; ++t) {
        const int j = tid + (t << 8);
        if (j < n) row[j] = f2bf(v[t] * inv);
        else if (j < zend) row[j] = 0;
    }
}

// O[row] += partials, rows 1024..4095; one block per row, float4 lanes
__global__ __launch_bounds__(256) void reduce_pv(float* __restrict__ O,
                                                 const float* __restrict__ P) {
    const int r = blockIdx.x;  // 0..3071
    const int row = 1024 + r;
    const int col = threadIdx.x * 4;
    float4 a = *(const float4*)(O + (size_t)row * 1024 + col);
    const float4 b1 = *(const float4*)(P + (size_t)r * 1024 + col);
    a.x += b1.x; a.y += b1.y; a.z += b1.z; a.w += b1.w;
    if (row >= 2048) {
        const float4 b2 = *(const float4*)(P + (size_t)3072 * 1024 +
                                           (size_t)(row - 2048) * 1024 + col);
        a.x += b2.x; a.y += b2.y; a.z += b2.z; a.w += b2.w;
    }
    if (row >= 3072) {
        const float4 b3 = *(const float4*)(P + (size_t)5120 * 1024 +
                                           (size_t)(row - 3072) * 1024 + col);
        a.x += b3.x; a.y += b3.y; a.z += b3.z; a.w += b3.w;
    }
    *(float4*)(O + (size_t)row * 1024 + col) = a;
}

extern "C" void kernel_launch(void* const* d_in, const int* in_sizes, int n_in,
                              void* d_out, int out_size, void* d_ws, size_t ws_size,
                              hipStream_t stream) {
    const float* x  = (const float*)d_in[0];
    const float* Wq = (const float*)d_in[1];
    const float* Wk = (const float*)d_in[2];
    const float* Wv = (const float*)d_in[3];

    // ws: xb 8MB | Wt 6MB | QK [4096][2048] 16MB | Vt 8MB | S 32MB | Ppart 24MB = 94 MB
    u16* xb    = (u16*)d_ws;
    u16* Wt    = xb  + (size_t)SEQ * DIM;
    u16* QK    = Wt  + (size_t)3072 * DIM;
    u16* Vt    = QK  + (size_t)SEQ * 2048;
    u16* S     = Vt  + (size_t)DIM * SEQ;
    float* Ppart = (float*)(S + (size_t)SEQ * SEQ);

    cast_bf16<<<SEQ * DIM / 1024, 256, 0, stream>>>(x, xb);
    transpose_cast<<<dim3(32, 32, 3), 256, 0, stream>>>(Wq, Wk, Wv, Wt);

    // [Q|K] = x @ [Wq|Wk] (Q scaled 1/32); V columns stream out as V^T. 768 blocks.
    gemm_nt<0><<<dim3(24, 32), 256, 0, stream>>>(
        xb, Wt, QK, nullptr, Vt, DIM, DIM, 2048, DIM, 0.03125f);

    // S = Q @ K^T, lower-triangle blocks. 528 active blocks.
    gemm_nt<1><<<dim3(32, 32), 256, 0, stream>>>(
        QK, QK + 1024, S, nullptr, nullptr, 2048, 2048, SEQ, DIM, 1.0f);

    softmax_causal_bf16<<<SEQ, 256, 0, stream>>>(S);

    // O = P @ Vt^T, split-K (1024-chunks, causal-bounded). 640 active blocks.
    gemm_nt<2><<<dim3(8, 32, 4), 256, 0, stream>>>(
        S, Vt, d_out, Ppart, nullptr, SEQ, SEQ, DIM, SEQ, 1.0f);

    reduce_pv<<<3072, 256, 0, stream>>>((float*)d_out, Ppart);
}